// Round 1
// baseline (1508.874 us; speedup 1.0000x reference)
//
#include <hip/hip_runtime.h>

// Equivariant tensor-product edge convolution, e3nn-style.
// L_OUT=L_IN=[0,1,2], MUL=16 everywhere. 19 CG paths, all structure
// compile-time constant. HBM-bound on the 972.8 MB rbf_coeffs stream.

namespace {

constexpr int NP   = 19;
constexpr int R_DIM = 4864;   // per-edge rbf row
constexpr int FEAT  = 144;    // feat_in == feat_out
constexpr int YDIM  = 25;
constexpr int NCY   = 259;    // total CY entries (sum do*di over paths)
constexpr int ND    = 1104;   // total D entries  (sum 16*do over paths)

struct Path {
  int lo, li, lf, nlf, k;     // k = index of lf within this (lo,li)'s lf list
  int r_off, cg_off, in_off, d_off, cy_off;
};

// Path order matches the reference: lo outer, li middle, lf inner.
constexpr Path PATHS[NP] = {
  //lo li lf nlf k   r_off cg_off in_off d_off cy_off
  {0, 0, 0, 1, 0,     0,    0,   0,    0,    0},
  {0, 1, 1, 1, 0,   256,    1,  16,   16,    1},
  {0, 2, 2, 1, 0,   512,   10,  64,   32,    4},
  {1, 0, 1, 1, 0,   768,   35,   0,   48,    9},
  {1, 1, 0, 3, 0,  1024,   44,  16,   96,   12},
  {1, 1, 1, 3, 1,  1024,   53,  16,  144,   21},
  {1, 1, 2, 3, 2,  1024,   80,  16,  192,   30},
  {1, 2, 1, 3, 0,  1792,  125,  64,  240,   39},
  {1, 2, 2, 3, 1,  1792,  170,  64,  288,   54},
  {1, 2, 3, 3, 2,  1792,  245,  64,  336,   69},
  {2, 0, 2, 1, 0,  2560,  350,   0,  384,   84},
  {2, 1, 1, 3, 0,  2816,  375,  16,  464,   89},
  {2, 1, 2, 3, 1,  2816,  420,  16,  544,  104},
  {2, 1, 3, 3, 2,  2816,  495,  16,  624,  119},
  {2, 2, 0, 5, 0,  3584,  600,  64,  704,  134},
  {2, 2, 1, 5, 1,  3584,  625,  64,  784,  159},
  {2, 2, 2, 5, 2,  3584,  700,  64,  864,  184},
  {2, 2, 3, 5, 3,  3584,  825,  64,  944,  209},
  {2, 2, 4, 5, 4,  3584, 1000,  64, 1024,  234},
};

// ---- compile-time flat index tables for the CY and D phases ----

struct CYTab {
  short cg_base[NCY];
  unsigned char y_base[NCY];
  unsigned char df[NCY];
  unsigned char w[NCY];
};

constexpr CYTab make_cy() {
  CYTab T{};
  int j = 0;
  for (int p = 0; p < NP; ++p) {
    const int df = 2 * PATHS[p].lf + 1;
    const int di = 2 * PATHS[p].li + 1;
    const int dn = 2 * PATHS[p].lo + 1;
    for (int o = 0; o < dn; ++o)
      for (int i = 0; i < di; ++i) {
        T.cg_base[j] = (short)(PATHS[p].cg_off + (o * di + i) * df);
        T.y_base[j]  = (unsigned char)(PATHS[p].lf * PATHS[p].lf);
        T.df[j]      = (unsigned char)df;
        T.w[j]       = (unsigned char)p;   // w index == path index
        ++j;
      }
  }
  return T;
}
constexpr CYTab CYT = make_cy();

struct DTab {
  short cy_base[ND];
  unsigned char f_base[ND];
  unsigned char di[ND];
};

constexpr DTab make_d() {
  DTab T{};
  int j = 0;
  for (int p = 0; p < NP; ++p) {
    const int di = 2 * PATHS[p].li + 1;
    const int dn = 2 * PATHS[p].lo + 1;
    for (int v = 0; v < 16; ++v)          // entry order = d_off + v*do + o
      for (int o = 0; o < dn; ++o) {
        T.cy_base[j] = (short)(PATHS[p].cy_off + o * di);
        T.f_base[j]  = (unsigned char)(PATHS[p].in_off + v * di);
        T.di[j]      = (unsigned char)di;
        ++j;
      }
  }
  return T;
}
constexpr DTab DT = make_d();

} // namespace

__global__ __launch_bounds__(256)
void tp_conv_kernel(const float* __restrict__ features,
                    const float* __restrict__ rbf,
                    const float* __restrict__ Yg,
                    const float* __restrict__ cg,
                    const float* __restrict__ Wg,
                    const int*   __restrict__ pa,
                    const int*   __restrict__ pb,
                    float*       __restrict__ out)
{
  __shared__ float sR[R_DIM];   // 19456 B — the edge's rbf row
  __shared__ float sF[FEAT];
  __shared__ float sY[YDIM];
  __shared__ float sCY[NCY];
  __shared__ float sD[ND];

  const int e = blockIdx.x;
  const int t = threadIdx.x;
  const int a = pa[e];
  const int b = pb[e];

  // ---- stage: R row (coalesced float4), F[b], Y[e] ----
  {
    const float4* rs = (const float4*)(rbf + (size_t)e * R_DIM);
    float4* rd = (float4*)sR;
    #pragma unroll
    for (int j = t; j < R_DIM / 4; j += 256) rd[j] = rs[j];

    const float4* fs = (const float4*)(features + (size_t)b * FEAT);
    if (t < FEAT / 4) ((float4*)sF)[t] = fs[t];
    if (t < YDIM) sY[t] = Yg[(size_t)e * YDIM + t];
  }
  __syncthreads();

  // ---- CY[o,i] = W_p * sum_f C[o,i,f] * Y[f]  (259 entries) ----
  for (int j = t; j < NCY; j += 256) {
    const int df = CYT.df[j];
    const float* c = cg + CYT.cg_base[j];
    const float* y = sY + CYT.y_base[j];
    float s = 0.f;
    for (int f = 0; f < df; ++f) s += c[f] * y[f];
    sCY[j] = s * Wg[CYT.w[j]];
  }
  __syncthreads();

  // ---- D[v,o] = sum_i CY[o,i] * F[v,i]  (1104 entries) ----
  for (int j = t; j < ND; j += 256) {
    const int di = DT.di[j];
    const float* cyp = sCY + DT.cy_base[j];
    const float* fp  = sF + DT.f_base[j];
    float s = 0.f;
    for (int i = 0; i < di; ++i) s += cyp[i] * fp[i];
    sD[j] = s;
  }
  __syncthreads();

  // ---- main contraction: thread (u,v) does 69 FMAs over 19 paths ----
  const int v = t & 15;
  const int u = t >> 4;
  float acc[9];
  #pragma unroll
  for (int z = 0; z < 9; ++z) acc[z] = 0.f;

  #pragma unroll
  for (int p = 0; p < NP; ++p) {
    // R_p[u,v] = sR[r_off + (u*16+v)*nlf + k]; note u*16+v == t
    const float r = sR[PATHS[p].r_off + t * PATHS[p].nlf + PATHS[p].k];
    const int dn = 2 * PATHS[p].lo + 1;
    const int ab = (PATHS[p].lo == 0) ? 0 : (PATHS[p].lo == 1 ? 1 : 4);
    const int dbase = PATHS[p].d_off + v * dn;
    for (int o = 0; o < dn; ++o) acc[ab + o] += r * sD[dbase + o];
  }

  // ---- reduce over v: xor lanes 1,2,4,8 (within wave64) ----
  #pragma unroll
  for (int m = 1; m <= 8; m <<= 1) {
    #pragma unroll
    for (int z = 0; z < 9; ++z) acc[z] += __shfl_xor(acc[z], m, 64);
  }

  // ---- scatter-add into out[a] (v==0 lanes hold the result) ----
  if (v == 0) {
    float* op = out + (size_t)a * FEAT;
    atomicAdd(op + u, acc[0]);                      // lo=0: idx u
    #pragma unroll
    for (int o = 0; o < 3; ++o)
      atomicAdd(op + 16 + u * 3 + o, acc[1 + o]);   // lo=1
    #pragma unroll
    for (int o = 0; o < 5; ++o)
      atomicAdd(op + 64 + u * 5 + o, acc[4 + o]);   // lo=2
  }
}

extern "C" void kernel_launch(void* const* d_in, const int* in_sizes, int n_in,
                              void* d_out, int out_size, void* d_ws, size_t ws_size,
                              hipStream_t stream) {
  const float* features = (const float*)d_in[0];
  const float* rbf      = (const float*)d_in[1];
  const float* Yg       = (const float*)d_in[2];
  const float* cg       = (const float*)d_in[3];
  const float* Wg       = (const float*)d_in[4];
  const int*   pa       = (const int*)d_in[5];
  const int*   pb       = (const int*)d_in[6];
  float* out = (float*)d_out;

  const int E = in_sizes[5];   // 50000 edges

  // output is a scatter-add target: must start at zero (harness poisons it)
  hipMemsetAsync(d_out, 0, (size_t)out_size * sizeof(float), stream);

  tp_conv_kernel<<<E, 256, 0, stream>>>(features, rbf, Yg, cg, Wg, pa, pb, out);
}